// Round 5
// baseline (69.044 us; speedup 1.0000x reference)
//
#include <hip/hip_runtime.h>
#include <cstdint>
#include <cstddef>

#define SIGMA_INV 10.0f
#define EPS_C 1e-7f

constexpr int TDIM = 512;   // time bins
constexpr int ROWS2 = 16;   // rows per block (phase 1)
constexpr int PITCH = 513;  // LDS pitch (f32), conflict-free column reads
constexpr int NBLK = 512;   // grid = N/ROWS2 = TDIM
constexpr int MAXC = 256;   // max bucket size (actual ~16)

// One fused kernel: phase 1 (row cumsum + per-block SGT partials), device-wide
// barrier, phase 2 (per-k bucket reduction), phase 3 (last block combines).
__global__ __launch_bounds__(512, 4) void fused_kernel(
    const float* __restrict__ pmf, const float* __restrict__ times,
    const int* __restrict__ events, const float* __restrict__ bins,
    unsigned* __restrict__ counters,
    float* __restrict__ SGTp, float* __restrict__ scaleA,
    float* __restrict__ einvA, int* __restrict__ kidxA,
    float* __restrict__ nll_part, int* __restrict__ ev_part,
    float* __restrict__ rank_part, int* __restrict__ npair_part,
    float* __restrict__ out, int N)
{
    __shared__ __align__(16) char smem[ROWS2 * PITCH * 4];  // 32,832 B, reused per phase
    __shared__ float binsS[TDIM];
    __shared__ int karr[ROWS2];
    __shared__ float nllv[ROWS2];
    __shared__ int evv[ROWS2];
    __shared__ int ncl_sh;
    __shared__ float SGT_sh;
    __shared__ int CGT_sh;
    __shared__ int last_sh;

    float* tile = (float*)smem;
    const int tid = threadIdx.x;
    const int lane = tid & 63;
    const int wid = tid >> 6;            // 8 waves, 2 rows each
    const int b = blockIdx.x;
    const int i0 = b * ROWS2;

    binsS[tid] = bins[tid];              // TDIM == blockDim == 512

    // ---------------- phase 1: rows ----------------
    float4 A[2][2];
    #pragma unroll
    for (int r = 0; r < 2; ++r) {
        const int i = i0 + wid * 2 + r;
        const float4* p4 = (const float4*)(pmf + (size_t)i * TDIM + lane * 8);
        A[r][0] = p4[0];
        A[r][1] = p4[1];
    }
    #pragma unroll
    for (int r = 0; r < 2; ++r) {
        const int rl = wid * 2 + r;
        float c0 = A[r][0].x, c1 = c0 + A[r][0].y, c2 = c1 + A[r][0].z, c3 = c2 + A[r][0].w;
        float c4 = c3 + A[r][1].x, c5 = c4 + A[r][1].y, c6 = c5 + A[r][1].z, c7 = c6 + A[r][1].w;
        float v = c7;
        #pragma unroll
        for (int d = 1; d < 64; d <<= 1) {
            float u = __shfl_up(v, d);
            if (lane >= d) v += u;
        }
        const float excl = v - c7;           // exclusive prefix of lane sums
        float* t = tile + rl * PITCH + lane * 8;
        t[0] = c0 + excl; t[1] = c1 + excl; t[2] = c2 + excl; t[3] = c3 + excl;
        t[4] = c4 + excl; t[5] = c5 + excl; t[6] = c6 + excl; t[7] = c7 + excl;
    }
    __syncthreads();

    if (tid < ROWS2) {
        const int i = i0 + tid;
        const float t = times[i];
        // searchsorted(bins, t, side='left') on LDS-cached bins
        int lo = 0, hi = TDIM;
        while (lo < hi) {
            int mid = (lo + hi) >> 1;
            if (binsS[mid] < t) lo = mid + 1; else hi = mid;
        }
        int k = lo - 1;
        k = k < 0 ? 0 : (k > TDIM - 1 ? TDIM - 1 : k);
        const float cdf_at = tile[tid * PITCH + k];
        const float tot = tile[tid * PITCH + (TDIM - 1)];
        const float pmf_at = pmf[(size_t)i * TDIM + k];
        const float surv = tot - cdf_at + pmf_at;
        nllv[tid] = (events[i] == 1) ? -logf(pmf_at + EPS_C) : -logf(surv + EPS_C);
        evv[tid] = events[i];
        scaleA[i] = expf(-cdf_at * SIGMA_INV);
        einvA[i] = expf(cdf_at * SIGMA_INV);
        kidxA[i] = k;
        karr[tid] = k;
    }
    __syncthreads();

    // Column-owner accumulation: k = tid, 16 rows, deterministic order.
    float acc = 0.f;
    #pragma unroll
    for (int s = 0; s < ROWS2; ++s) {
        const float c = tile[s * PITCH + tid];
        if (tid < karr[s]) acc += expf(c * SIGMA_INV);
    }
    SGTp[(size_t)b * TDIM + tid] = acc;   // coalesced

    if (wid == 0) {
        float nv = (lane < ROWS2) ? nllv[lane] : 0.f;
        int ev = (lane < ROWS2) ? evv[lane] : 0;
        #pragma unroll
        for (int d = 8; d > 0; d >>= 1) {
            nv += __shfl_down(nv, d);
            ev += __shfl_down(ev, d);
        }
        if (lane == 0) { nll_part[b] = nv; ev_part[b] = ev; }
    }

    // ---------------- device-wide barrier ----------------
    __syncthreads();
    if (tid == 0) {
        __threadfence();
        __hip_atomic_fetch_add(&counters[0], 1u, __ATOMIC_ACQ_REL,
                               __HIP_MEMORY_SCOPE_AGENT);
        while (__hip_atomic_load(&counters[0], __ATOMIC_ACQUIRE,
                                 __HIP_MEMORY_SCOPE_AGENT) < (unsigned)NBLK) {
            __builtin_amdgcn_s_sleep(8);
        }
    }
    __syncthreads();

    // ---------------- phase 2: bucket k = b ----------------
    const int k = b;
    int* cj = (int*)smem;            // reuse tile (dead after barrier)
    int* oj = cj + MAXC;
    float* mt = (float*)(oj + MAXC);
    float* me = mt + MAXC;
    float* redf = me + MAXC;         // [8]
    float* red2f = redf + 8;         // [8]
    int* redi = (int*)(red2f + 8);   // [8]
    int* red2i = redi + 8;           // [8]

    if (tid == 0) ncl_sh = 0;
    __syncthreads();

    // SGT[k] = sum_b SGTp[b][k]; thread tid handles b = tid (NBLK == 512).
    float sv = SGTp[(size_t)tid * TDIM + k];
    #pragma unroll
    for (int d = 32; d > 0; d >>= 1) sv += __shfl_down(sv, d);
    if (lane == 0) redf[wid] = sv;

    int cnt = 0;
    const int4* kx4 = (const int4*)kidxA;
    #pragma unroll
    for (int it = 0; it < 4; ++it) {
        const int ch = it * 512 + tid;      // N/4 == 2048 chunks
        const int4 kx = kx4[ch];
        const int j0 = ch * 4;
        cnt += (kx.x > k) + (kx.y > k) + (kx.z > k) + (kx.w > k);
        if (kx.x == k) { int p = atomicAdd(&ncl_sh, 1); if (p < MAXC) cj[p] = j0 + 0; }
        if (kx.y == k) { int p = atomicAdd(&ncl_sh, 1); if (p < MAXC) cj[p] = j0 + 1; }
        if (kx.z == k) { int p = atomicAdd(&ncl_sh, 1); if (p < MAXC) cj[p] = j0 + 2; }
        if (kx.w == k) { int p = atomicAdd(&ncl_sh, 1); if (p < MAXC) cj[p] = j0 + 3; }
    }
    #pragma unroll
    for (int d = 32; d > 0; d >>= 1) cnt += __shfl_down(cnt, d);
    if (lane == 0) redi[wid] = cnt;
    __syncthreads();
    if (tid == 0) {
        float s8 = 0.f; int c8 = 0;
        #pragma unroll
        for (int w = 0; w < 8; ++w) { s8 += redf[w]; c8 += redi[w]; }
        SGT_sh = s8; CGT_sh = c8;
    }
    __syncthreads();

    const int nc = ncl_sh < MAXC ? ncl_sh : MAXC;
    // Rank-reorder members by j (deterministic despite atomic collection).
    if (tid < nc) {
        const int myj = cj[tid];
        int r = 0;
        for (int m = 0; m < nc; ++m) r += (cj[m] < myj) ? 1 : 0;
        oj[r] = myj;
    }
    __syncthreads();
    if (tid < nc) { mt[tid] = times[oj[tid]]; me[tid] = einvA[oj[tid]]; }
    __syncthreads();

    float pi = 0.f;
    int vf = 0;
    if (tid < nc) {
        const int i = oj[tid];
        const float ti = mt[tid];
        float s = 0.f;
        int c = 0;
        for (int m = 0; m < nc; ++m) {
            if (mt[m] > ti) { s += me[m]; c++; }
        }
        const int C = CGT_sh + c;
        if (events[i] == 1 && C > 0) {
            vf = 1;
            pi = scaleA[i] * (SGT_sh + s) / (float)C;
        }
    }
    #pragma unroll
    for (int d = 32; d > 0; d >>= 1) {
        pi += __shfl_down(pi, d);
        vf += __shfl_down(vf, d);
    }
    if (lane == 0) { red2f[wid] = pi; red2i[wid] = vf; }
    __syncthreads();
    if (tid == 0) {
        float s8 = 0.f; int c8 = 0;
        #pragma unroll
        for (int w = 0; w < 8; ++w) { s8 += red2f[w]; c8 += red2i[w]; }
        rank_part[k] = s8;
        npair_part[k] = c8;
    }

    // ---------------- phase 3: last block combines ----------------
    __syncthreads();
    if (tid == 0) {
        __threadfence();
        unsigned old = __hip_atomic_fetch_add(&counters[1], 1u, __ATOMIC_ACQ_REL,
                                              __HIP_MEMORY_SCOPE_AGENT);
        last_sh = (old == (unsigned)(NBLK - 1)) ? 1 : 0;
    }
    __syncthreads();
    if (last_sh) {
        double* sd1 = (double*)smem;      // 4 KB
        double* sd2 = sd1 + 512;          // 4 KB
        int* si1 = (int*)(sd2 + 512);     // 2 KB
        int* si2 = si1 + 512;             // 2 KB
        sd1[tid] = (double)nll_part[tid];
        sd2[tid] = (double)rank_part[tid];
        si1[tid] = npair_part[tid];
        si2[tid] = ev_part[tid];
        __syncthreads();
        for (int off = 256; off > 0; off >>= 1) {
            if (tid < off) {
                sd1[tid] += sd1[tid + off];
                sd2[tid] += sd2[tid + off];
                si1[tid] += si1[tid + off];
                si2[tid] += si2[tid + off];
            }
            __syncthreads();
        }
        if (tid == 0) {
            double loss = sd1[0] / (double)N;
            if (si2[0] > 1 && si1[0] > 0) loss += 0.5 * sd2[0] / (double)si1[0];
            out[0] = (float)loss;
        }
    }
}

extern "C" void kernel_launch(void* const* d_in, const int* in_sizes, int n_in,
                              void* d_out, int out_size, void* d_ws, size_t ws_size,
                              hipStream_t stream) {
    const float* pmf = (const float*)d_in[0];
    const float* times = (const float*)d_in[1];
    const int* events = (const int*)d_in[2];
    const float* bins = (const float*)d_in[3];
    const int N = in_sizes[1];  // 8192

    char* ws = (char*)d_ws;
    unsigned* counters = (unsigned*)ws;                  // 2 uints (256B pad)
    float* SGTp = (float*)(ws + 256);                    // NBLK * TDIM
    float* scaleA = SGTp + (size_t)NBLK * TDIM;          // N
    float* einvA = scaleA + N;                           // N
    float* nll_part = einvA + N;                         // NBLK
    float* rank_part = nll_part + NBLK;                  // TDIM
    int* kidxA = (int*)(rank_part + TDIM);               // N
    int* ev_part = kidxA + N;                            // NBLK
    int* npair_part = ev_part + NBLK;                    // TDIM

    hipMemsetAsync(counters, 0, 2 * sizeof(unsigned), stream);
    fused_kernel<<<NBLK, 512, 0, stream>>>(
        pmf, times, events, bins, counters, SGTp, scaleA, einvA, kidxA,
        nll_part, ev_part, rank_part, npair_part, (float*)d_out, N);
}

// Round 6
// 56.982 us; speedup vs baseline: 1.2117x; 1.2117x over previous
//
#include <hip/hip_runtime.h>
#include <cstdint>
#include <cstddef>

#define SIGMA_INV 10.0f
#define EPS_C 1e-7f

constexpr int TDIM = 512;   // time bins
constexpr int ROWS2 = 16;   // rows per block (phase 1)
constexpr int PITCH = 513;  // LDS pitch (f32), conflict-free column reads
constexpr int NBLK = 512;   // grid = N/ROWS2 = TDIM
constexpr int MAXC = 256;   // max bucket size (actual ~16)

// One fused kernel: phase 1 (row cumsum + per-block SGT partials), device-wide
// barrier (RELEASE add / RELAXED spin / single ACQUIRE — no per-iteration L2
// invalidate), phase 2 (per-k bucket reduction), phase 3 (last block combines).
__global__ __launch_bounds__(512, 4) void fused_kernel(
    const float* __restrict__ pmf, const float* __restrict__ times,
    const int* __restrict__ events, const float* __restrict__ bins,
    unsigned* __restrict__ counters,
    float* __restrict__ SGTp, float* __restrict__ scaleA,
    float* __restrict__ einvA, int* __restrict__ kidxA,
    float* __restrict__ nll_part, int* __restrict__ ev_part,
    float* __restrict__ rank_part, int* __restrict__ npair_part,
    float* __restrict__ out, int N)
{
    __shared__ __align__(16) char smem[ROWS2 * PITCH * 4];  // 32,832 B, reused per phase
    __shared__ float binsS[TDIM];
    __shared__ int karr[ROWS2];
    __shared__ float nllv[ROWS2];
    __shared__ int evv[ROWS2];
    __shared__ int ncl_sh;
    __shared__ float SGT_sh;
    __shared__ int CGT_sh;
    __shared__ int last_sh;

    float* tile = (float*)smem;
    const int tid = threadIdx.x;
    const int lane = tid & 63;
    const int wid = tid >> 6;            // 8 waves, 2 rows each
    const int b = blockIdx.x;
    const int i0 = b * ROWS2;

    binsS[tid] = bins[tid];              // TDIM == blockDim == 512

    // ---------------- phase 1: rows ----------------
    float4 A[2][2];
    #pragma unroll
    for (int r = 0; r < 2; ++r) {
        const int i = i0 + wid * 2 + r;
        const float4* p4 = (const float4*)(pmf + (size_t)i * TDIM + lane * 8);
        A[r][0] = p4[0];
        A[r][1] = p4[1];
    }
    #pragma unroll
    for (int r = 0; r < 2; ++r) {
        const int rl = wid * 2 + r;
        float c0 = A[r][0].x, c1 = c0 + A[r][0].y, c2 = c1 + A[r][0].z, c3 = c2 + A[r][0].w;
        float c4 = c3 + A[r][1].x, c5 = c4 + A[r][1].y, c6 = c5 + A[r][1].z, c7 = c6 + A[r][1].w;
        float v = c7;
        #pragma unroll
        for (int d = 1; d < 64; d <<= 1) {
            float u = __shfl_up(v, d);
            if (lane >= d) v += u;
        }
        const float excl = v - c7;           // exclusive prefix of lane sums
        float* t = tile + rl * PITCH + lane * 8;
        t[0] = c0 + excl; t[1] = c1 + excl; t[2] = c2 + excl; t[3] = c3 + excl;
        t[4] = c4 + excl; t[5] = c5 + excl; t[6] = c6 + excl; t[7] = c7 + excl;
    }
    __syncthreads();

    if (tid < ROWS2) {
        const int i = i0 + tid;
        const float t = times[i];
        // searchsorted(bins, t, side='left') on LDS-cached bins
        int lo = 0, hi = TDIM;
        while (lo < hi) {
            int mid = (lo + hi) >> 1;
            if (binsS[mid] < t) lo = mid + 1; else hi = mid;
        }
        int k = lo - 1;
        k = k < 0 ? 0 : (k > TDIM - 1 ? TDIM - 1 : k);
        const float cdf_at = tile[tid * PITCH + k];
        const float tot = tile[tid * PITCH + (TDIM - 1)];
        const float pmf_at = pmf[(size_t)i * TDIM + k];
        const float surv = tot - cdf_at + pmf_at;
        nllv[tid] = (events[i] == 1) ? -logf(pmf_at + EPS_C) : -logf(surv + EPS_C);
        evv[tid] = events[i];
        scaleA[i] = expf(-cdf_at * SIGMA_INV);
        einvA[i] = expf(cdf_at * SIGMA_INV);
        kidxA[i] = k;
        karr[tid] = k;
    }
    __syncthreads();

    // Column-owner accumulation: k = tid, 16 rows, deterministic order.
    float acc = 0.f;
    #pragma unroll
    for (int s = 0; s < ROWS2; ++s) {
        const float c = tile[s * PITCH + tid];
        if (tid < karr[s]) acc += expf(c * SIGMA_INV);
    }
    SGTp[(size_t)b * TDIM + tid] = acc;   // coalesced

    if (wid == 0) {
        float nv = (lane < ROWS2) ? nllv[lane] : 0.f;
        int ev = (lane < ROWS2) ? evv[lane] : 0;
        #pragma unroll
        for (int d = 8; d > 0; d >>= 1) {
            nv += __shfl_down(nv, d);
            ev += __shfl_down(ev, d);
        }
        if (lane == 0) { nll_part[b] = nv; ev_part[b] = ev; }
    }

    // ---------------- device-wide barrier ----------------
    __syncthreads();
    if (tid == 0) {
        // arrival: RELEASE makes phase-1 writes visible (one L2 writeback)
        __hip_atomic_fetch_add(&counters[0], 1u, __ATOMIC_RELEASE,
                               __HIP_MEMORY_SCOPE_AGENT);
        // spin RELAXED: no per-iteration cache maintenance
        while (__hip_atomic_load(&counters[0], __ATOMIC_RELAXED,
                                 __HIP_MEMORY_SCOPE_AGENT) < (unsigned)NBLK) {
            __builtin_amdgcn_s_sleep(2);
        }
        // single ACQUIRE to pull in all released writes
        (void)__hip_atomic_load(&counters[0], __ATOMIC_ACQUIRE,
                                __HIP_MEMORY_SCOPE_AGENT);
    }
    __syncthreads();

    // ---------------- phase 2: bucket k = b ----------------
    const int k = b;
    int* cj = (int*)smem;            // reuse tile (dead after barrier)
    int* oj = cj + MAXC;
    float* mt = (float*)(oj + MAXC);
    float* me = mt + MAXC;
    float* redf = me + MAXC;         // [8]
    float* red2f = redf + 8;         // [8]
    int* redi = (int*)(red2f + 8);   // [8]
    int* red2i = redi + 8;           // [8]

    if (tid == 0) ncl_sh = 0;
    __syncthreads();

    // SGT[k] = sum_b SGTp[b][k]; thread tid handles b = tid (NBLK == 512).
    float sv = SGTp[(size_t)tid * TDIM + k];
    #pragma unroll
    for (int d = 32; d > 0; d >>= 1) sv += __shfl_down(sv, d);
    if (lane == 0) redf[wid] = sv;

    int cnt = 0;
    const int4* kx4 = (const int4*)kidxA;
    #pragma unroll
    for (int it = 0; it < 4; ++it) {
        const int ch = it * 512 + tid;      // N/4 == 2048 chunks
        const int4 kx = kx4[ch];
        const int j0 = ch * 4;
        cnt += (kx.x > k) + (kx.y > k) + (kx.z > k) + (kx.w > k);
        if (kx.x == k) { int p = atomicAdd(&ncl_sh, 1); if (p < MAXC) cj[p] = j0 + 0; }
        if (kx.y == k) { int p = atomicAdd(&ncl_sh, 1); if (p < MAXC) cj[p] = j0 + 1; }
        if (kx.z == k) { int p = atomicAdd(&ncl_sh, 1); if (p < MAXC) cj[p] = j0 + 2; }
        if (kx.w == k) { int p = atomicAdd(&ncl_sh, 1); if (p < MAXC) cj[p] = j0 + 3; }
    }
    #pragma unroll
    for (int d = 32; d > 0; d >>= 1) cnt += __shfl_down(cnt, d);
    if (lane == 0) redi[wid] = cnt;
    __syncthreads();
    if (tid == 0) {
        float s8 = 0.f; int c8 = 0;
        #pragma unroll
        for (int w = 0; w < 8; ++w) { s8 += redf[w]; c8 += redi[w]; }
        SGT_sh = s8; CGT_sh = c8;
    }
    __syncthreads();

    const int nc = ncl_sh < MAXC ? ncl_sh : MAXC;
    // Rank-reorder members by j (deterministic despite atomic collection).
    if (tid < nc) {
        const int myj = cj[tid];
        int r = 0;
        for (int m = 0; m < nc; ++m) r += (cj[m] < myj) ? 1 : 0;
        oj[r] = myj;
    }
    __syncthreads();
    if (tid < nc) { mt[tid] = times[oj[tid]]; me[tid] = einvA[oj[tid]]; }
    __syncthreads();

    float pi = 0.f;
    int vf = 0;
    if (tid < nc) {
        const int i = oj[tid];
        const float ti = mt[tid];
        float s = 0.f;
        int c = 0;
        for (int m = 0; m < nc; ++m) {
            if (mt[m] > ti) { s += me[m]; c++; }
        }
        const int C = CGT_sh + c;
        if (events[i] == 1 && C > 0) {
            vf = 1;
            pi = scaleA[i] * (SGT_sh + s) / (float)C;
        }
    }
    #pragma unroll
    for (int d = 32; d > 0; d >>= 1) {
        pi += __shfl_down(pi, d);
        vf += __shfl_down(vf, d);
    }
    if (lane == 0) { red2f[wid] = pi; red2i[wid] = vf; }
    __syncthreads();
    if (tid == 0) {
        float s8 = 0.f; int c8 = 0;
        #pragma unroll
        for (int w = 0; w < 8; ++w) { s8 += red2f[w]; c8 += red2i[w]; }
        rank_part[k] = s8;
        npair_part[k] = c8;
    }

    // ---------------- phase 3: last block combines ----------------
    __syncthreads();
    if (tid == 0) {
        unsigned old = __hip_atomic_fetch_add(&counters[1], 1u, __ATOMIC_RELEASE,
                                              __HIP_MEMORY_SCOPE_AGENT);
        if (old == (unsigned)(NBLK - 1)) {
            // only the last block pays the ACQUIRE (L2 inv) to see all partials
            (void)__hip_atomic_load(&counters[1], __ATOMIC_ACQUIRE,
                                    __HIP_MEMORY_SCOPE_AGENT);
            last_sh = 1;
        } else {
            last_sh = 0;
        }
    }
    __syncthreads();
    if (last_sh) {
        double* sd1 = (double*)smem;      // 4 KB
        double* sd2 = sd1 + 512;          // 4 KB
        int* si1 = (int*)(sd2 + 512);     // 2 KB
        int* si2 = si1 + 512;             // 2 KB
        sd1[tid] = (double)nll_part[tid];
        sd2[tid] = (double)rank_part[tid];
        si1[tid] = npair_part[tid];
        si2[tid] = ev_part[tid];
        __syncthreads();
        for (int off = 256; off > 0; off >>= 1) {
            if (tid < off) {
                sd1[tid] += sd1[tid + off];
                sd2[tid] += sd2[tid + off];
                si1[tid] += si1[tid + off];
                si2[tid] += si2[tid + off];
            }
            __syncthreads();
        }
        if (tid == 0) {
            double loss = sd1[0] / (double)N;
            if (si2[0] > 1 && si1[0] > 0) loss += 0.5 * sd2[0] / (double)si1[0];
            out[0] = (float)loss;
        }
    }
}

extern "C" void kernel_launch(void* const* d_in, const int* in_sizes, int n_in,
                              void* d_out, int out_size, void* d_ws, size_t ws_size,
                              hipStream_t stream) {
    const float* pmf = (const float*)d_in[0];
    const float* times = (const float*)d_in[1];
    const int* events = (const int*)d_in[2];
    const float* bins = (const float*)d_in[3];
    const int N = in_sizes[1];  // 8192

    char* ws = (char*)d_ws;
    unsigned* counters = (unsigned*)ws;                  // 2 uints (256B pad)
    float* SGTp = (float*)(ws + 256);                    // NBLK * TDIM
    float* scaleA = SGTp + (size_t)NBLK * TDIM;          // N
    float* einvA = scaleA + N;                           // N
    float* nll_part = einvA + N;                         // NBLK
    float* rank_part = nll_part + NBLK;                  // TDIM
    int* kidxA = (int*)(rank_part + TDIM);               // N
    int* ev_part = kidxA + N;                            // NBLK
    int* npair_part = ev_part + NBLK;                    // TDIM

    hipMemsetAsync(counters, 0, 2 * sizeof(unsigned), stream);
    fused_kernel<<<NBLK, 512, 0, stream>>>(
        pmf, times, events, bins, counters, SGTp, scaleA, einvA, kidxA,
        nll_part, ev_part, rank_part, npair_part, (float*)d_out, N);
}

// Round 7
// 56.354 us; speedup vs baseline: 1.2252x; 1.0111x over previous
//
#include <hip/hip_runtime.h>
#include <cstdint>
#include <cstddef>

#define SIGMA_INV 10.0f
#define EPS_C 1e-7f

constexpr int TDIM = 512;   // time bins
constexpr int ROWS2 = 16;   // rows per block (phase 1)
constexpr int PITCH = 513;  // LDS pitch (f32), conflict-free column reads
constexpr int NBLK = 512;   // grid = N/ROWS2 = TDIM
constexpr int MAXC = 256;   // max bucket size (actual ~16)

// One fused kernel: phase 1 (row cumsum + per-block SGT partials), device-wide
// barrier (RELEASE add / slow RELAXED poll / single ACQUIRE), phase 2 (per-k
// bucket reduction), phase 3 (last block combines).
// Barrier lesson (R5/R6): agent-scope polls bypass L2 and hammer ONE LLC
// slice; poll every ~50ns from 512 waves congests the slice and the arrival
// atomics queue behind it. Poll slowly (s_sleep(64) ~= 1.7us).
__global__ __launch_bounds__(512, 4) void fused_kernel(
    const float* __restrict__ pmf, const float* __restrict__ times,
    const int* __restrict__ events, const float* __restrict__ bins,
    unsigned* __restrict__ counters,
    float* __restrict__ SGTp, float* __restrict__ scaleA,
    float* __restrict__ einvA, int* __restrict__ kidxA,
    float* __restrict__ nll_part, int* __restrict__ ev_part,
    float* __restrict__ rank_part, int* __restrict__ npair_part,
    float* __restrict__ out, int N)
{
    __shared__ __align__(16) char smem[ROWS2 * PITCH * 4];  // 32,832 B, reused per phase
    __shared__ float binsS[TDIM];
    __shared__ int karr[ROWS2];
    __shared__ float nllv[ROWS2];
    __shared__ int evv[ROWS2];
    __shared__ int ncl_sh;
    __shared__ float SGT_sh;
    __shared__ int CGT_sh;
    __shared__ int last_sh;

    float* tile = (float*)smem;
    const int tid = threadIdx.x;
    const int lane = tid & 63;
    const int wid = tid >> 6;            // 8 waves, 2 rows each
    const int b = blockIdx.x;
    const int i0 = b * ROWS2;

    binsS[tid] = bins[tid];              // TDIM == blockDim == 512

    // ---------------- phase 1: rows ----------------
    float4 A[2][2];
    #pragma unroll
    for (int r = 0; r < 2; ++r) {
        const int i = i0 + wid * 2 + r;
        const float4* p4 = (const float4*)(pmf + (size_t)i * TDIM + lane * 8);
        A[r][0] = p4[0];
        A[r][1] = p4[1];
    }
    #pragma unroll
    for (int r = 0; r < 2; ++r) {
        const int rl = wid * 2 + r;
        float c0 = A[r][0].x, c1 = c0 + A[r][0].y, c2 = c1 + A[r][0].z, c3 = c2 + A[r][0].w;
        float c4 = c3 + A[r][1].x, c5 = c4 + A[r][1].y, c6 = c5 + A[r][1].z, c7 = c6 + A[r][1].w;
        float v = c7;
        #pragma unroll
        for (int d = 1; d < 64; d <<= 1) {
            float u = __shfl_up(v, d);
            if (lane >= d) v += u;
        }
        const float excl = v - c7;           // exclusive prefix of lane sums
        float* t = tile + rl * PITCH + lane * 8;
        t[0] = c0 + excl; t[1] = c1 + excl; t[2] = c2 + excl; t[3] = c3 + excl;
        t[4] = c4 + excl; t[5] = c5 + excl; t[6] = c6 + excl; t[7] = c7 + excl;
    }
    __syncthreads();

    if (tid < ROWS2) {
        const int i = i0 + tid;
        const float t = times[i];
        // searchsorted(bins, t, side='left') on LDS-cached bins
        int lo = 0, hi = TDIM;
        while (lo < hi) {
            int mid = (lo + hi) >> 1;
            if (binsS[mid] < t) lo = mid + 1; else hi = mid;
        }
        int k = lo - 1;
        k = k < 0 ? 0 : (k > TDIM - 1 ? TDIM - 1 : k);
        const float cdf_at = tile[tid * PITCH + k];
        const float tot = tile[tid * PITCH + (TDIM - 1)];
        const float pmf_at = pmf[(size_t)i * TDIM + k];
        const float surv = tot - cdf_at + pmf_at;
        nllv[tid] = (events[i] == 1) ? -logf(pmf_at + EPS_C) : -logf(surv + EPS_C);
        evv[tid] = events[i];
        scaleA[i] = expf(-cdf_at * SIGMA_INV);
        einvA[i] = expf(cdf_at * SIGMA_INV);
        kidxA[i] = k;
        karr[tid] = k;
    }
    __syncthreads();

    // Column-owner accumulation: k = tid, 16 rows, deterministic order.
    float acc = 0.f;
    #pragma unroll
    for (int s = 0; s < ROWS2; ++s) {
        const float c = tile[s * PITCH + tid];
        if (tid < karr[s]) acc += expf(c * SIGMA_INV);
    }
    SGTp[(size_t)b * TDIM + tid] = acc;   // coalesced

    if (wid == 0) {
        float nv = (lane < ROWS2) ? nllv[lane] : 0.f;
        int ev = (lane < ROWS2) ? evv[lane] : 0;
        #pragma unroll
        for (int d = 8; d > 0; d >>= 1) {
            nv += __shfl_down(nv, d);
            ev += __shfl_down(ev, d);
        }
        if (lane == 0) { nll_part[b] = nv; ev_part[b] = ev; }
    }

    // ---------------- device-wide barrier ----------------
    __syncthreads();
    if (tid == 0) {
        // arrival: RELEASE makes phase-1 writes visible (one L2 writeback)
        __hip_atomic_fetch_add(&counters[0], 1u, __ATOMIC_RELEASE,
                               __HIP_MEMORY_SCOPE_AGENT);
        // slow poll: ~1.7us per iteration; keeps the counter's LLC slice idle
        while (__hip_atomic_load(&counters[0], __ATOMIC_RELAXED,
                                 __HIP_MEMORY_SCOPE_AGENT) < (unsigned)NBLK) {
            __builtin_amdgcn_s_sleep(64);
        }
        // single ACQUIRE to pull in all released writes
        (void)__hip_atomic_load(&counters[0], __ATOMIC_ACQUIRE,
                                __HIP_MEMORY_SCOPE_AGENT);
    }
    __syncthreads();

    // ---------------- phase 2: bucket k = b ----------------
    const int k = b;
    int* cj = (int*)smem;            // reuse tile (dead after barrier)
    int* oj = cj + MAXC;
    float* mt = (float*)(oj + MAXC);
    float* me = mt + MAXC;
    float* redf = me + MAXC;         // [8]
    float* red2f = redf + 8;         // [8]
    int* redi = (int*)(red2f + 8);   // [8]
    int* red2i = redi + 8;           // [8]

    if (tid == 0) ncl_sh = 0;
    __syncthreads();

    // SGT[k] = sum_b SGTp[b][k]; thread tid handles b = tid (NBLK == 512).
    float sv = SGTp[(size_t)tid * TDIM + k];
    #pragma unroll
    for (int d = 32; d > 0; d >>= 1) sv += __shfl_down(sv, d);
    if (lane == 0) redf[wid] = sv;

    int cnt = 0;
    const int4* kx4 = (const int4*)kidxA;
    #pragma unroll
    for (int it = 0; it < 4; ++it) {
        const int ch = it * 512 + tid;      // N/4 == 2048 chunks
        const int4 kx = kx4[ch];
        const int j0 = ch * 4;
        cnt += (kx.x > k) + (kx.y > k) + (kx.z > k) + (kx.w > k);
        if (kx.x == k) { int p = atomicAdd(&ncl_sh, 1); if (p < MAXC) cj[p] = j0 + 0; }
        if (kx.y == k) { int p = atomicAdd(&ncl_sh, 1); if (p < MAXC) cj[p] = j0 + 1; }
        if (kx.z == k) { int p = atomicAdd(&ncl_sh, 1); if (p < MAXC) cj[p] = j0 + 2; }
        if (kx.w == k) { int p = atomicAdd(&ncl_sh, 1); if (p < MAXC) cj[p] = j0 + 3; }
    }
    #pragma unroll
    for (int d = 32; d > 0; d >>= 1) cnt += __shfl_down(cnt, d);
    if (lane == 0) redi[wid] = cnt;
    __syncthreads();
    if (tid == 0) {
        float s8 = 0.f; int c8 = 0;
        #pragma unroll
        for (int w = 0; w < 8; ++w) { s8 += redf[w]; c8 += redi[w]; }
        SGT_sh = s8; CGT_sh = c8;
    }
    __syncthreads();

    const int nc = ncl_sh < MAXC ? ncl_sh : MAXC;
    // Rank-reorder members by j (deterministic despite atomic collection).
    if (tid < nc) {
        const int myj = cj[tid];
        int r = 0;
        for (int m = 0; m < nc; ++m) r += (cj[m] < myj) ? 1 : 0;
        oj[r] = myj;
    }
    __syncthreads();
    if (tid < nc) { mt[tid] = times[oj[tid]]; me[tid] = einvA[oj[tid]]; }
    __syncthreads();

    float pi = 0.f;
    int vf = 0;
    if (tid < nc) {
        const int i = oj[tid];
        const float ti = mt[tid];
        float s = 0.f;
        int c = 0;
        for (int m = 0; m < nc; ++m) {
            if (mt[m] > ti) { s += me[m]; c++; }
        }
        const int C = CGT_sh + c;
        if (events[i] == 1 && C > 0) {
            vf = 1;
            pi = scaleA[i] * (SGT_sh + s) / (float)C;
        }
    }
    #pragma unroll
    for (int d = 32; d > 0; d >>= 1) {
        pi += __shfl_down(pi, d);
        vf += __shfl_down(vf, d);
    }
    if (lane == 0) { red2f[wid] = pi; red2i[wid] = vf; }
    __syncthreads();
    if (tid == 0) {
        float s8 = 0.f; int c8 = 0;
        #pragma unroll
        for (int w = 0; w < 8; ++w) { s8 += red2f[w]; c8 += red2i[w]; }
        rank_part[k] = s8;
        npair_part[k] = c8;
    }

    // ---------------- phase 3: last block combines ----------------
    __syncthreads();
    if (tid == 0) {
        unsigned old = __hip_atomic_fetch_add(&counters[1], 1u, __ATOMIC_RELEASE,
                                              __HIP_MEMORY_SCOPE_AGENT);
        if (old == (unsigned)(NBLK - 1)) {
            // only the last block pays the ACQUIRE (L2 inv) to see all partials
            (void)__hip_atomic_load(&counters[1], __ATOMIC_ACQUIRE,
                                    __HIP_MEMORY_SCOPE_AGENT);
            last_sh = 1;
        } else {
            last_sh = 0;
        }
    }
    __syncthreads();
    if (last_sh) {
        double* sd1 = (double*)smem;      // 4 KB
        double* sd2 = sd1 + 512;          // 4 KB
        int* si1 = (int*)(sd2 + 512);     // 2 KB
        int* si2 = si1 + 512;             // 2 KB
        sd1[tid] = (double)nll_part[tid];
        sd2[tid] = (double)rank_part[tid];
        si1[tid] = npair_part[tid];
        si2[tid] = ev_part[tid];
        __syncthreads();
        for (int off = 256; off > 0; off >>= 1) {
            if (tid < off) {
                sd1[tid] += sd1[tid + off];
                sd2[tid] += sd2[tid + off];
                si1[tid] += si1[tid + off];
                si2[tid] += si2[tid + off];
            }
            __syncthreads();
        }
        if (tid == 0) {
            double loss = sd1[0] / (double)N;
            if (si2[0] > 1 && si1[0] > 0) loss += 0.5 * sd2[0] / (double)si1[0];
            out[0] = (float)loss;
        }
    }
}

extern "C" void kernel_launch(void* const* d_in, const int* in_sizes, int n_in,
                              void* d_out, int out_size, void* d_ws, size_t ws_size,
                              hipStream_t stream) {
    const float* pmf = (const float*)d_in[0];
    const float* times = (const float*)d_in[1];
    const int* events = (const int*)d_in[2];
    const float* bins = (const float*)d_in[3];
    const int N = in_sizes[1];  // 8192

    char* ws = (char*)d_ws;
    unsigned* counters = (unsigned*)ws;                  // 2 uints (256B pad)
    float* SGTp = (float*)(ws + 256);                    // NBLK * TDIM
    float* scaleA = SGTp + (size_t)NBLK * TDIM;          // N
    float* einvA = scaleA + N;                           // N
    float* nll_part = einvA + N;                         // NBLK
    float* rank_part = nll_part + NBLK;                  // TDIM
    int* kidxA = (int*)(rank_part + TDIM);               // N
    int* ev_part = kidxA + N;                            // NBLK
    int* npair_part = ev_part + NBLK;                    // TDIM

    hipMemsetAsync(counters, 0, 2 * sizeof(unsigned), stream);
    fused_kernel<<<NBLK, 512, 0, stream>>>(
        pmf, times, events, bins, counters, SGTp, scaleA, einvA, kidxA,
        nll_part, ev_part, rank_part, npair_part, (float*)d_out, N);
}

// Round 8
// 45.721 us; speedup vs baseline: 1.5101x; 1.2326x over previous
//
#include <hip/hip_runtime.h>
#include <cstdint>
#include <cstddef>

#define SIGMA_INV 10.0f
#define EPS_C 1e-7f

constexpr int TDIM = 512;   // time bins
constexpr int ROWS2 = 16;   // rows per block (phase 1)
constexpr int PITCH = 513;  // LDS pitch (f32), conflict-free column reads
constexpr int NBLK = 512;   // grid = N/ROWS2 = TDIM
constexpr int MAXC = 256;   // max bucket size (actual ~16)

// Cross-block data discipline (R5-R7 lesson): agent-scope RELEASE/ACQUIRE on
// gfx950 emit buffer_wbl2 / buffer_inv (full per-XCD L2 writeback/invalidate).
// 512 blocks x 2 maintenance ops serialized per-XCD L2 was the ~40us stall.
// Fix: ALL cross-block-visible data uses relaxed agent-scope atomics (sc1
// write-through stores / L2-bypass loads) -> zero cache maintenance; the
// __syncthreads() pre-barrier vmcnt(0) drain provides completion ordering.
__device__ __forceinline__ void stf(float* p, float v) {
    __hip_atomic_store(p, v, __ATOMIC_RELAXED, __HIP_MEMORY_SCOPE_AGENT);
}
__device__ __forceinline__ void sti(int* p, int v) {
    __hip_atomic_store(p, v, __ATOMIC_RELAXED, __HIP_MEMORY_SCOPE_AGENT);
}
__device__ __forceinline__ float ldf(const float* p) {
    return __hip_atomic_load(p, __ATOMIC_RELAXED, __HIP_MEMORY_SCOPE_AGENT);
}
__device__ __forceinline__ int ldi(const int* p) {
    return __hip_atomic_load(p, __ATOMIC_RELAXED, __HIP_MEMORY_SCOPE_AGENT);
}

__global__ __launch_bounds__(512, 4) void fused_kernel(
    const float* __restrict__ pmf, const float* __restrict__ times,
    const int* __restrict__ events, const float* __restrict__ bins,
    unsigned* __restrict__ counters,
    float* __restrict__ SGTp, float* __restrict__ scaleA,
    float* __restrict__ einvA, int* __restrict__ kidxA,
    float* __restrict__ nll_part, int* __restrict__ ev_part,
    float* __restrict__ rank_part, int* __restrict__ npair_part,
    float* __restrict__ out, int N)
{
    __shared__ __align__(16) char smem[ROWS2 * PITCH * 4];  // 32,832 B, reused per phase
    __shared__ float binsS[TDIM];
    __shared__ int karr[ROWS2];
    __shared__ float nllv[ROWS2];
    __shared__ int evv[ROWS2];
    __shared__ int ncl_sh;
    __shared__ float SGT_sh;
    __shared__ int CGT_sh;
    __shared__ int last_sh;

    float* tile = (float*)smem;
    const int tid = threadIdx.x;
    const int lane = tid & 63;
    const int wid = tid >> 6;            // 8 waves, 2 rows each
    const int b = blockIdx.x;
    const int i0 = b * ROWS2;

    binsS[tid] = bins[tid];              // TDIM == blockDim == 512

    // ---------------- phase 1: rows ----------------
    float4 A[2][2];
    #pragma unroll
    for (int r = 0; r < 2; ++r) {
        const int i = i0 + wid * 2 + r;
        const float4* p4 = (const float4*)(pmf + (size_t)i * TDIM + lane * 8);
        A[r][0] = p4[0];
        A[r][1] = p4[1];
    }
    #pragma unroll
    for (int r = 0; r < 2; ++r) {
        const int rl = wid * 2 + r;
        float c0 = A[r][0].x, c1 = c0 + A[r][0].y, c2 = c1 + A[r][0].z, c3 = c2 + A[r][0].w;
        float c4 = c3 + A[r][1].x, c5 = c4 + A[r][1].y, c6 = c5 + A[r][1].z, c7 = c6 + A[r][1].w;
        float v = c7;
        #pragma unroll
        for (int d = 1; d < 64; d <<= 1) {
            float u = __shfl_up(v, d);
            if (lane >= d) v += u;
        }
        const float excl = v - c7;           // exclusive prefix of lane sums
        float* t = tile + rl * PITCH + lane * 8;
        t[0] = c0 + excl; t[1] = c1 + excl; t[2] = c2 + excl; t[3] = c3 + excl;
        t[4] = c4 + excl; t[5] = c5 + excl; t[6] = c6 + excl; t[7] = c7 + excl;
    }
    __syncthreads();

    if (tid < ROWS2) {
        const int i = i0 + tid;
        const float t = times[i];
        // searchsorted(bins, t, side='left') on LDS-cached bins
        int lo = 0, hi = TDIM;
        while (lo < hi) {
            int mid = (lo + hi) >> 1;
            if (binsS[mid] < t) lo = mid + 1; else hi = mid;
        }
        int k = lo - 1;
        k = k < 0 ? 0 : (k > TDIM - 1 ? TDIM - 1 : k);
        const float cdf_at = tile[tid * PITCH + k];
        const float tot = tile[tid * PITCH + (TDIM - 1)];
        const float pmf_at = pmf[(size_t)i * TDIM + k];
        const float surv = tot - cdf_at + pmf_at;
        nllv[tid] = (events[i] == 1) ? -logf(pmf_at + EPS_C) : -logf(surv + EPS_C);
        evv[tid] = events[i];
        stf(scaleA + i, expf(-cdf_at * SIGMA_INV));
        stf(einvA + i, expf(cdf_at * SIGMA_INV));
        sti(kidxA + i, k);
        karr[tid] = k;
    }
    __syncthreads();

    // Column-owner accumulation: k = tid, 16 rows, deterministic order.
    float acc = 0.f;
    #pragma unroll
    for (int s = 0; s < ROWS2; ++s) {
        const float c = tile[s * PITCH + tid];
        if (tid < karr[s]) acc += expf(c * SIGMA_INV);
    }
    stf(SGTp + (size_t)b * TDIM + tid, acc);   // coalesced sc1 write-through

    if (wid == 0) {
        float nv = (lane < ROWS2) ? nllv[lane] : 0.f;
        int ev = (lane < ROWS2) ? evv[lane] : 0;
        #pragma unroll
        for (int d = 8; d > 0; d >>= 1) {
            nv += __shfl_down(nv, d);
            ev += __shfl_down(ev, d);
        }
        if (lane == 0) { stf(nll_part + b, nv); sti(ev_part + b, ev); }
    }

    // ---------------- device-wide barrier (zero cache maintenance) ----------
    __syncthreads();   // per-wave vmcnt(0) drain: all sc1 stores complete
    if (tid == 0) {
        asm volatile("s_waitcnt vmcnt(0)" ::: "memory");
        __hip_atomic_fetch_add(&counters[0], 1u, __ATOMIC_RELAXED,
                               __HIP_MEMORY_SCOPE_AGENT);
        while (__hip_atomic_load(&counters[0], __ATOMIC_RELAXED,
                                 __HIP_MEMORY_SCOPE_AGENT) < (unsigned)NBLK) {
            __builtin_amdgcn_s_sleep(16);
        }
    }
    __syncthreads();

    // ---------------- phase 2: bucket k = b ----------------
    const int k = b;
    int* cj = (int*)smem;            // reuse tile (dead after barrier)
    int* oj = cj + MAXC;
    float* mt = (float*)(oj + MAXC);
    float* me = mt + MAXC;
    float* redf = me + MAXC;         // [8]
    float* red2f = redf + 8;         // [8]
    int* redi = (int*)(red2f + 8);   // [8]
    int* red2i = redi + 8;           // [8]

    if (tid == 0) ncl_sh = 0;
    __syncthreads();

    // SGT[k] = sum_b SGTp[b][k]; thread tid handles b = tid (NBLK == 512).
    float sv = ldf(SGTp + (size_t)tid * TDIM + k);
    #pragma unroll
    for (int d = 32; d > 0; d >>= 1) sv += __shfl_down(sv, d);
    if (lane == 0) redf[wid] = sv;

    int cnt = 0;
    #pragma unroll
    for (int it = 0; it < 4; ++it) {
        const int j0 = (it * 512 + tid) * 4;    // N/4 == 2048 chunks
        const int k0 = ldi(kidxA + j0 + 0);
        const int k1 = ldi(kidxA + j0 + 1);
        const int k2 = ldi(kidxA + j0 + 2);
        const int k3 = ldi(kidxA + j0 + 3);
        cnt += (k0 > k) + (k1 > k) + (k2 > k) + (k3 > k);
        if (k0 == k) { int p = atomicAdd(&ncl_sh, 1); if (p < MAXC) cj[p] = j0 + 0; }
        if (k1 == k) { int p = atomicAdd(&ncl_sh, 1); if (p < MAXC) cj[p] = j0 + 1; }
        if (k2 == k) { int p = atomicAdd(&ncl_sh, 1); if (p < MAXC) cj[p] = j0 + 2; }
        if (k3 == k) { int p = atomicAdd(&ncl_sh, 1); if (p < MAXC) cj[p] = j0 + 3; }
    }
    #pragma unroll
    for (int d = 32; d > 0; d >>= 1) cnt += __shfl_down(cnt, d);
    if (lane == 0) redi[wid] = cnt;
    __syncthreads();
    if (tid == 0) {
        float s8 = 0.f; int c8 = 0;
        #pragma unroll
        for (int w = 0; w < 8; ++w) { s8 += redf[w]; c8 += redi[w]; }
        SGT_sh = s8; CGT_sh = c8;
    }
    __syncthreads();

    const int nc = ncl_sh < MAXC ? ncl_sh : MAXC;
    // Rank-reorder members by j (deterministic despite atomic collection).
    if (tid < nc) {
        const int myj = cj[tid];
        int r = 0;
        for (int m = 0; m < nc; ++m) r += (cj[m] < myj) ? 1 : 0;
        oj[r] = myj;
    }
    __syncthreads();
    if (tid < nc) { mt[tid] = times[oj[tid]]; me[tid] = ldf(einvA + oj[tid]); }
    __syncthreads();

    float pi = 0.f;
    int vf = 0;
    if (tid < nc) {
        const int i = oj[tid];
        const float ti = mt[tid];
        float s = 0.f;
        int c = 0;
        for (int m = 0; m < nc; ++m) {
            if (mt[m] > ti) { s += me[m]; c++; }
        }
        const int C = CGT_sh + c;
        if (events[i] == 1 && C > 0) {
            vf = 1;
            pi = ldf(scaleA + i) * (SGT_sh + s) / (float)C;
        }
    }
    #pragma unroll
    for (int d = 32; d > 0; d >>= 1) {
        pi += __shfl_down(pi, d);
        vf += __shfl_down(vf, d);
    }
    if (lane == 0) { red2f[wid] = pi; red2i[wid] = vf; }
    __syncthreads();
    if (tid == 0) {
        float s8 = 0.f; int c8 = 0;
        #pragma unroll
        for (int w = 0; w < 8; ++w) { s8 += red2f[w]; c8 += red2i[w]; }
        stf(rank_part + k, s8);
        sti(npair_part + k, c8);
    }

    // ---------------- phase 3: last-block ticket (no spin) ----------------
    __syncthreads();   // drains the rank/npair sc1 stores (vmcnt(0) per wave)
    if (tid == 0) {
        asm volatile("s_waitcnt vmcnt(0)" ::: "memory");
        unsigned old = __hip_atomic_fetch_add(&counters[1], 1u, __ATOMIC_RELAXED,
                                              __HIP_MEMORY_SCOPE_AGENT);
        last_sh = (old == (unsigned)(NBLK - 1)) ? 1 : 0;
    }
    __syncthreads();
    if (last_sh) {
        double* sd1 = (double*)smem;      // 4 KB
        double* sd2 = sd1 + 512;          // 4 KB
        int* si1 = (int*)(sd2 + 512);     // 2 KB
        int* si2 = si1 + 512;             // 2 KB
        sd1[tid] = (double)ldf(nll_part + tid);
        sd2[tid] = (double)ldf(rank_part + tid);
        si1[tid] = ldi(npair_part + tid);
        si2[tid] = ldi(ev_part + tid);
        __syncthreads();
        for (int off = 256; off > 0; off >>= 1) {
            if (tid < off) {
                sd1[tid] += sd1[tid + off];
                sd2[tid] += sd2[tid + off];
                si1[tid] += si1[tid + off];
                si2[tid] += si2[tid + off];
            }
            __syncthreads();
        }
        if (tid == 0) {
            double loss = sd1[0] / (double)N;
            if (si2[0] > 1 && si1[0] > 0) loss += 0.5 * sd2[0] / (double)si1[0];
            out[0] = (float)loss;
        }
    }
}

extern "C" void kernel_launch(void* const* d_in, const int* in_sizes, int n_in,
                              void* d_out, int out_size, void* d_ws, size_t ws_size,
                              hipStream_t stream) {
    const float* pmf = (const float*)d_in[0];
    const float* times = (const float*)d_in[1];
    const int* events = (const int*)d_in[2];
    const float* bins = (const float*)d_in[3];
    const int N = in_sizes[1];  // 8192

    char* ws = (char*)d_ws;
    unsigned* counters = (unsigned*)ws;                  // 2 uints (256B pad)
    float* SGTp = (float*)(ws + 256);                    // NBLK * TDIM
    float* scaleA = SGTp + (size_t)NBLK * TDIM;          // N
    float* einvA = scaleA + N;                           // N
    float* nll_part = einvA + N;                         // NBLK
    float* rank_part = nll_part + NBLK;                  // TDIM
    int* kidxA = (int*)(rank_part + TDIM);               // N
    int* ev_part = kidxA + N;                            // NBLK
    int* npair_part = ev_part + NBLK;                    // TDIM

    hipMemsetAsync(counters, 0, 2 * sizeof(unsigned), stream);
    fused_kernel<<<NBLK, 512, 0, stream>>>(
        pmf, times, events, bins, counters, SGTp, scaleA, einvA, kidxA,
        nll_part, ev_part, rank_part, npair_part, (float*)d_out, N);
}

// Round 9
// 28.056 us; speedup vs baseline: 2.4609x; 1.6296x over previous
//
#include <hip/hip_runtime.h>
#include <cstdint>
#include <cstddef>

#define SIGMA_INV 10.0f
#define EPS_C 1e-7f

constexpr int TDIM = 512;   // time bins
constexpr int ROWS2 = 16;   // rows per block (K1)
constexpr int PITCH = 513;  // LDS pitch (f32), conflict-free column reads
constexpr int NBLK = 512;   // K1/K2 grid = N/ROWS2 = TDIM
constexpr int MAXC = 256;   // max bucket size (actual ~16)

// R5-R8 lesson: grid-wide barriers lose on this chip (serialized same-line
// RMW arrival + sc1 L2-bypass for ALL cross-block data). Kernel boundary is
// the cheap synchronizer. Only the tiny final-combine uses the proven
// zero-maintenance ticket: sc1 write-through partials + relaxed RMW ticket.
__device__ __forceinline__ void stf(float* p, float v) {
    __hip_atomic_store(p, v, __ATOMIC_RELAXED, __HIP_MEMORY_SCOPE_AGENT);
}
__device__ __forceinline__ void sti(int* p, int v) {
    __hip_atomic_store(p, v, __ATOMIC_RELAXED, __HIP_MEMORY_SCOPE_AGENT);
}
__device__ __forceinline__ float ldf(const float* p) {
    return __hip_atomic_load(p, __ATOMIC_RELAXED, __HIP_MEMORY_SCOPE_AGENT);
}
__device__ __forceinline__ int ldi(const int* p) {
    return __hip_atomic_load(p, __ATOMIC_RELAXED, __HIP_MEMORY_SCOPE_AGENT);
}

// K1: per-row cumsum (tree scan) into LDS tile; nll/scale/einv/kidx; per-block
// partial SGTp[b][k]. Normal stores — K1->K2 kernel boundary publishes them.
__global__ __launch_bounds__(512, 4) void rows_kernel(
    const float* __restrict__ pmf, const float* __restrict__ times,
    const int* __restrict__ events, const float* __restrict__ bins,
    unsigned* __restrict__ counters,
    float* __restrict__ SGTp, float* __restrict__ scaleA,
    float* __restrict__ einvA, int* __restrict__ kidxA,
    float* __restrict__ nll_part, int* __restrict__ ev_part, int N)
{
    __shared__ float tile[ROWS2 * PITCH];   // 32,832 B
    __shared__ float binsS[TDIM];
    __shared__ int karr[ROWS2];
    __shared__ float nllv[ROWS2];
    __shared__ int evv[ROWS2];
    const int tid = threadIdx.x;
    const int lane = tid & 63;
    const int wid = tid >> 6;            // 8 waves, 2 rows each
    const int b = blockIdx.x;
    const int i0 = b * ROWS2;

    if (b == 0 && tid == 0) {            // zero the K2 ticket (replaces memset)
        __hip_atomic_store(&counters[0], 0u, __ATOMIC_RELAXED,
                           __HIP_MEMORY_SCOPE_AGENT);
    }

    binsS[tid] = bins[tid];              // TDIM == blockDim == 512

    float4 A[2][2];
    #pragma unroll
    for (int r = 0; r < 2; ++r) {
        const int i = i0 + wid * 2 + r;
        const float4* p4 = (const float4*)(pmf + (size_t)i * TDIM + lane * 8);
        A[r][0] = p4[0];
        A[r][1] = p4[1];
    }
    #pragma unroll
    for (int r = 0; r < 2; ++r) {
        const int rl = wid * 2 + r;
        float c0 = A[r][0].x, c1 = c0 + A[r][0].y, c2 = c1 + A[r][0].z, c3 = c2 + A[r][0].w;
        float c4 = c3 + A[r][1].x, c5 = c4 + A[r][1].y, c6 = c5 + A[r][1].z, c7 = c6 + A[r][1].w;
        float v = c7;
        #pragma unroll
        for (int d = 1; d < 64; d <<= 1) {
            float u = __shfl_up(v, d);
            if (lane >= d) v += u;
        }
        const float excl = v - c7;           // exclusive prefix of lane sums
        float* t = tile + rl * PITCH + lane * 8;
        t[0] = c0 + excl; t[1] = c1 + excl; t[2] = c2 + excl; t[3] = c3 + excl;
        t[4] = c4 + excl; t[5] = c5 + excl; t[6] = c6 + excl; t[7] = c7 + excl;
    }
    __syncthreads();

    if (tid < ROWS2) {
        const int i = i0 + tid;
        const float t = times[i];
        // searchsorted(bins, t, side='left') on LDS-cached bins
        int lo = 0, hi = TDIM;
        while (lo < hi) {
            int mid = (lo + hi) >> 1;
            if (binsS[mid] < t) lo = mid + 1; else hi = mid;
        }
        int k = lo - 1;
        k = k < 0 ? 0 : (k > TDIM - 1 ? TDIM - 1 : k);
        const float cdf_at = tile[tid * PITCH + k];
        const float tot = tile[tid * PITCH + (TDIM - 1)];
        const float pmf_at = pmf[(size_t)i * TDIM + k];
        const float surv = tot - cdf_at + pmf_at;
        nllv[tid] = (events[i] == 1) ? -logf(pmf_at + EPS_C) : -logf(surv + EPS_C);
        evv[tid] = events[i];
        scaleA[i] = expf(-cdf_at * SIGMA_INV);
        einvA[i] = expf(cdf_at * SIGMA_INV);
        kidxA[i] = k;
        karr[tid] = k;
    }
    __syncthreads();

    // Column-owner accumulation: k = tid, 16 rows, deterministic order.
    float acc = 0.f;
    #pragma unroll
    for (int s = 0; s < ROWS2; ++s) {
        const float c = tile[s * PITCH + tid];
        if (tid < karr[s]) acc += expf(c * SIGMA_INV);
    }
    SGTp[(size_t)b * TDIM + tid] = acc;   // coalesced

    if (wid == 0) {
        float nv = (lane < ROWS2) ? nllv[lane] : 0.f;
        int ev = (lane < ROWS2) ? evv[lane] : 0;
        #pragma unroll
        for (int d = 8; d > 0; d >>= 1) {
            nv += __shfl_down(nv, d);
            ev += __shfl_down(ev, d);
        }
        if (lane == 0) { nll_part[b] = nv; ev_part[b] = ev; }
    }
}

// K2: block k reduces SGTp[:,k] (L2-cached loads), scans kidx (int4, L2),
// does the exact in-bucket correction, stores rank/npair partials (sc1), and
// the last-ticket block combines everything and writes the scalar loss.
__global__ __launch_bounds__(512, 4) void bucket_final_kernel(
    const float* __restrict__ SGTp, const float* __restrict__ times,
    const int* __restrict__ events, const int* __restrict__ kidxA,
    const float* __restrict__ scaleA, const float* __restrict__ einvA,
    const float* __restrict__ nll_part, const int* __restrict__ ev_part,
    unsigned* __restrict__ counters,
    float* __restrict__ rank_part, int* __restrict__ npair_part,
    float* __restrict__ out, int N)
{
    __shared__ float redf[8];
    __shared__ int redi[8];
    __shared__ float red2f[8];
    __shared__ int red2i[8];
    __shared__ int cj[MAXC], oj[MAXC];
    __shared__ float mt[MAXC], me[MAXC];
    __shared__ int ncl_sh;
    __shared__ float SGT_sh;
    __shared__ int CGT_sh;
    __shared__ int last_sh;
    __shared__ double sd1[NBLK];     // final combine (last block only)
    __shared__ double sd2[NBLK];
    __shared__ int si1[NBLK];
    __shared__ int si2[NBLK];

    const int k = blockIdx.x;
    const int tid = threadIdx.x;
    const int lane = tid & 63;
    const int wid = tid >> 6;

    if (tid == 0) ncl_sh = 0;
    __syncthreads();

    // SGT[k] = sum_b SGTp[b][k]; thread tid handles b = tid (NBLK == 512).
    float sv = SGTp[(size_t)tid * TDIM + k];
    #pragma unroll
    for (int d = 32; d > 0; d >>= 1) sv += __shfl_down(sv, d);
    if (lane == 0) redf[wid] = sv;

    int cnt = 0;
    const int4* kx4 = (const int4*)kidxA;
    #pragma unroll
    for (int it = 0; it < 4; ++it) {
        const int ch = it * 512 + tid;      // N/4 == 2048 chunks
        const int4 kx = kx4[ch];
        const int j0 = ch * 4;
        cnt += (kx.x > k) + (kx.y > k) + (kx.z > k) + (kx.w > k);
        if (kx.x == k) { int p = atomicAdd(&ncl_sh, 1); if (p < MAXC) cj[p] = j0 + 0; }
        if (kx.y == k) { int p = atomicAdd(&ncl_sh, 1); if (p < MAXC) cj[p] = j0 + 1; }
        if (kx.z == k) { int p = atomicAdd(&ncl_sh, 1); if (p < MAXC) cj[p] = j0 + 2; }
        if (kx.w == k) { int p = atomicAdd(&ncl_sh, 1); if (p < MAXC) cj[p] = j0 + 3; }
    }
    #pragma unroll
    for (int d = 32; d > 0; d >>= 1) cnt += __shfl_down(cnt, d);
    if (lane == 0) redi[wid] = cnt;
    __syncthreads();
    if (tid == 0) {
        float s8 = 0.f; int c8 = 0;
        #pragma unroll
        for (int w = 0; w < 8; ++w) { s8 += redf[w]; c8 += redi[w]; }
        SGT_sh = s8; CGT_sh = c8;
    }
    __syncthreads();

    const int nc = ncl_sh < MAXC ? ncl_sh : MAXC;
    // Rank-reorder members by j (deterministic despite atomic collection).
    if (tid < nc) {
        const int myj = cj[tid];
        int r = 0;
        for (int m = 0; m < nc; ++m) r += (cj[m] < myj) ? 1 : 0;
        oj[r] = myj;
    }
    __syncthreads();
    if (tid < nc) { mt[tid] = times[oj[tid]]; me[tid] = einvA[oj[tid]]; }
    __syncthreads();

    float pi = 0.f;
    int vf = 0;
    if (tid < nc) {
        const int i = oj[tid];
        const float ti = mt[tid];
        float s = 0.f;
        int c = 0;
        for (int m = 0; m < nc; ++m) {
            if (mt[m] > ti) { s += me[m]; c++; }
        }
        const int C = CGT_sh + c;
        if (events[i] == 1 && C > 0) {
            vf = 1;
            pi = scaleA[i] * (SGT_sh + s) / (float)C;
        }
    }
    #pragma unroll
    for (int d = 32; d > 0; d >>= 1) {
        pi += __shfl_down(pi, d);
        vf += __shfl_down(vf, d);
    }
    if (lane == 0) { red2f[wid] = pi; red2i[wid] = vf; }
    __syncthreads();
    if (tid == 0) {
        float s8 = 0.f; int c8 = 0;
        #pragma unroll
        for (int w = 0; w < 8; ++w) { s8 += red2f[w]; c8 += red2i[w]; }
        stf(rank_part + k, s8);      // sc1 write-through: visible w/o flush
        sti(npair_part + k, c8);
    }

    // Last-ticket block combines (zero-maintenance ticket, R8-proven).
    __syncthreads();
    if (tid == 0) {
        asm volatile("s_waitcnt vmcnt(0)" ::: "memory");
        unsigned old = __hip_atomic_fetch_add(&counters[0], 1u, __ATOMIC_RELAXED,
                                              __HIP_MEMORY_SCOPE_AGENT);
        last_sh = (old == (unsigned)(NBLK - 1)) ? 1 : 0;
    }
    __syncthreads();
    if (last_sh) {
        sd1[tid] = (double)nll_part[tid];       // K1 data: normal loads OK
        si2[tid] = ev_part[tid];
        sd2[tid] = (double)ldf(rank_part + tid); // K2 peers: sc1 loads
        si1[tid] = ldi(npair_part + tid);
        __syncthreads();
        for (int off = 256; off > 0; off >>= 1) {
            if (tid < off) {
                sd1[tid] += sd1[tid + off];
                sd2[tid] += sd2[tid + off];
                si1[tid] += si1[tid + off];
                si2[tid] += si2[tid + off];
            }
            __syncthreads();
        }
        if (tid == 0) {
            double loss = sd1[0] / (double)N;
            if (si2[0] > 1 && si1[0] > 0) loss += 0.5 * sd2[0] / (double)si1[0];
            out[0] = (float)loss;
        }
    }
}

extern "C" void kernel_launch(void* const* d_in, const int* in_sizes, int n_in,
                              void* d_out, int out_size, void* d_ws, size_t ws_size,
                              hipStream_t stream) {
    const float* pmf = (const float*)d_in[0];
    const float* times = (const float*)d_in[1];
    const int* events = (const int*)d_in[2];
    const float* bins = (const float*)d_in[3];
    const int N = in_sizes[1];  // 8192

    char* ws = (char*)d_ws;
    unsigned* counters = (unsigned*)ws;                  // 1 uint (256B pad)
    float* SGTp = (float*)(ws + 256);                    // NBLK * TDIM
    float* scaleA = SGTp + (size_t)NBLK * TDIM;          // N
    float* einvA = scaleA + N;                           // N
    float* nll_part = einvA + N;                         // NBLK
    float* rank_part = nll_part + NBLK;                  // TDIM
    int* kidxA = (int*)(rank_part + TDIM);               // N
    int* ev_part = kidxA + N;                            // NBLK
    int* npair_part = ev_part + NBLK;                    // TDIM

    rows_kernel<<<NBLK, 512, 0, stream>>>(
        pmf, times, events, bins, counters, SGTp, scaleA, einvA, kidxA,
        nll_part, ev_part, N);
    bucket_final_kernel<<<NBLK, 512, 0, stream>>>(
        SGTp, times, events, kidxA, scaleA, einvA, nll_part, ev_part,
        counters, rank_part, npair_part, (float*)d_out, N);
}

// Round 10
// 23.609 us; speedup vs baseline: 2.9244x; 1.1883x over previous
//
#include <hip/hip_runtime.h>
#include <cstdint>
#include <cstddef>

#define SIGMA_INV 10.0f
#define EPS_C 1e-7f

constexpr int TDIM = 512;   // time bins
constexpr int ROWS2 = 16;   // rows per block (K1)
constexpr int PITCH = 513;  // LDS pitch (f32), conflict-free column reads
constexpr int NBLK = 512;   // K1/K2 grid = N/ROWS2 = TDIM
constexpr int MAXC = 256;   // max bucket size (actual ~16)

// R5-R9 lesson: grid barriers AND same-line atomic tickets are suspected to
// serialize (~512 RMWs to one LLC line per convergence point). This round:
// ZERO global atomics — kernel boundaries are the only synchronizer.

// K1: per-row cumsum (tree scan) into LDS tile; nll/scale/einv/kidx; per-block
// partial SGTp[b][k]. Normal stores — kernel boundary publishes them.
__global__ __launch_bounds__(512, 4) void rows_kernel(
    const float* __restrict__ pmf, const float* __restrict__ times,
    const int* __restrict__ events, const float* __restrict__ bins,
    float* __restrict__ SGTp, float* __restrict__ scaleA,
    float* __restrict__ einvA, int* __restrict__ kidxA,
    float* __restrict__ nll_part, int* __restrict__ ev_part, int N)
{
    __shared__ float tile[ROWS2 * PITCH];   // 32,832 B
    __shared__ float binsS[TDIM];
    __shared__ int karr[ROWS2];
    __shared__ float nllv[ROWS2];
    __shared__ int evv[ROWS2];
    const int tid = threadIdx.x;
    const int lane = tid & 63;
    const int wid = tid >> 6;            // 8 waves, 2 rows each
    const int b = blockIdx.x;
    const int i0 = b * ROWS2;

    binsS[tid] = bins[tid];              // TDIM == blockDim == 512

    float4 A[2][2];
    #pragma unroll
    for (int r = 0; r < 2; ++r) {
        const int i = i0 + wid * 2 + r;
        const float4* p4 = (const float4*)(pmf + (size_t)i * TDIM + lane * 8);
        A[r][0] = p4[0];
        A[r][1] = p4[1];
    }
    #pragma unroll
    for (int r = 0; r < 2; ++r) {
        const int rl = wid * 2 + r;
        float c0 = A[r][0].x, c1 = c0 + A[r][0].y, c2 = c1 + A[r][0].z, c3 = c2 + A[r][0].w;
        float c4 = c3 + A[r][1].x, c5 = c4 + A[r][1].y, c6 = c5 + A[r][1].z, c7 = c6 + A[r][1].w;
        float v = c7;
        #pragma unroll
        for (int d = 1; d < 64; d <<= 1) {
            float u = __shfl_up(v, d);
            if (lane >= d) v += u;
        }
        const float excl = v - c7;           // exclusive prefix of lane sums
        float* t = tile + rl * PITCH + lane * 8;
        t[0] = c0 + excl; t[1] = c1 + excl; t[2] = c2 + excl; t[3] = c3 + excl;
        t[4] = c4 + excl; t[5] = c5 + excl; t[6] = c6 + excl; t[7] = c7 + excl;
    }
    __syncthreads();

    if (tid < ROWS2) {
        const int i = i0 + tid;
        const float t = times[i];
        // searchsorted(bins, t, side='left') on LDS-cached bins
        int lo = 0, hi = TDIM;
        while (lo < hi) {
            int mid = (lo + hi) >> 1;
            if (binsS[mid] < t) lo = mid + 1; else hi = mid;
        }
        int k = lo - 1;
        k = k < 0 ? 0 : (k > TDIM - 1 ? TDIM - 1 : k);
        const float cdf_at = tile[tid * PITCH + k];
        const float tot = tile[tid * PITCH + (TDIM - 1)];
        const float pmf_at = pmf[(size_t)i * TDIM + k];
        const float surv = tot - cdf_at + pmf_at;
        nllv[tid] = (events[i] == 1) ? -logf(pmf_at + EPS_C) : -logf(surv + EPS_C);
        evv[tid] = events[i];
        scaleA[i] = expf(-cdf_at * SIGMA_INV);
        einvA[i] = expf(cdf_at * SIGMA_INV);
        kidxA[i] = k;
        karr[tid] = k;
    }
    __syncthreads();

    // Column-owner accumulation: k = tid, 16 rows, deterministic order.
    float acc = 0.f;
    #pragma unroll
    for (int s = 0; s < ROWS2; ++s) {
        const float c = tile[s * PITCH + tid];
        if (tid < karr[s]) acc += expf(c * SIGMA_INV);
    }
    SGTp[(size_t)b * TDIM + tid] = acc;   // coalesced

    if (wid == 0) {
        float nv = (lane < ROWS2) ? nllv[lane] : 0.f;
        int ev = (lane < ROWS2) ? evv[lane] : 0;
        #pragma unroll
        for (int d = 8; d > 0; d >>= 1) {
            nv += __shfl_down(nv, d);
            ev += __shfl_down(ev, d);
        }
        if (lane == 0) { nll_part[b] = nv; ev_part[b] = ev; }
    }
}

// K2: block k reduces SGTp[:,k] (L2-cached), scans kidx (int4, L2), exact
// in-bucket correction, writes rank/npair partials with NORMAL stores.
__global__ __launch_bounds__(512, 4) void bucket_kernel(
    const float* __restrict__ SGTp, const float* __restrict__ times,
    const int* __restrict__ events, const int* __restrict__ kidxA,
    const float* __restrict__ scaleA, const float* __restrict__ einvA,
    float* __restrict__ rank_part, int* __restrict__ npair_part, int N)
{
    __shared__ float redf[8];
    __shared__ int redi[8];
    __shared__ float red2f[8];
    __shared__ int red2i[8];
    __shared__ int cj[MAXC], oj[MAXC];
    __shared__ float mt[MAXC], me[MAXC];
    __shared__ int ncl_sh;
    __shared__ float SGT_sh;
    __shared__ int CGT_sh;

    const int k = blockIdx.x;
    const int tid = threadIdx.x;
    const int lane = tid & 63;
    const int wid = tid >> 6;

    if (tid == 0) ncl_sh = 0;
    __syncthreads();

    // SGT[k] = sum_b SGTp[b][k]; thread tid handles b = tid (NBLK == 512).
    float sv = SGTp[(size_t)tid * TDIM + k];
    #pragma unroll
    for (int d = 32; d > 0; d >>= 1) sv += __shfl_down(sv, d);
    if (lane == 0) redf[wid] = sv;

    int cnt = 0;
    const int4* kx4 = (const int4*)kidxA;
    #pragma unroll
    for (int it = 0; it < 4; ++it) {
        const int ch = it * 512 + tid;      // N/4 == 2048 chunks
        const int4 kx = kx4[ch];
        const int j0 = ch * 4;
        cnt += (kx.x > k) + (kx.y > k) + (kx.z > k) + (kx.w > k);
        if (kx.x == k) { int p = atomicAdd(&ncl_sh, 1); if (p < MAXC) cj[p] = j0 + 0; }
        if (kx.y == k) { int p = atomicAdd(&ncl_sh, 1); if (p < MAXC) cj[p] = j0 + 1; }
        if (kx.z == k) { int p = atomicAdd(&ncl_sh, 1); if (p < MAXC) cj[p] = j0 + 2; }
        if (kx.w == k) { int p = atomicAdd(&ncl_sh, 1); if (p < MAXC) cj[p] = j0 + 3; }
    }
    #pragma unroll
    for (int d = 32; d > 0; d >>= 1) cnt += __shfl_down(cnt, d);
    if (lane == 0) redi[wid] = cnt;
    __syncthreads();
    if (tid == 0) {
        float s8 = 0.f; int c8 = 0;
        #pragma unroll
        for (int w = 0; w < 8; ++w) { s8 += redf[w]; c8 += redi[w]; }
        SGT_sh = s8; CGT_sh = c8;
    }
    __syncthreads();

    const int nc = ncl_sh < MAXC ? ncl_sh : MAXC;
    // Rank-reorder members by j (deterministic despite atomic collection).
    if (tid < nc) {
        const int myj = cj[tid];
        int r = 0;
        for (int m = 0; m < nc; ++m) r += (cj[m] < myj) ? 1 : 0;
        oj[r] = myj;
    }
    __syncthreads();
    if (tid < nc) { mt[tid] = times[oj[tid]]; me[tid] = einvA[oj[tid]]; }
    __syncthreads();

    float pi = 0.f;
    int vf = 0;
    if (tid < nc) {
        const int i = oj[tid];
        const float ti = mt[tid];
        float s = 0.f;
        int c = 0;
        for (int m = 0; m < nc; ++m) {
            if (mt[m] > ti) { s += me[m]; c++; }
        }
        const int C = CGT_sh + c;
        if (events[i] == 1 && C > 0) {
            vf = 1;
            pi = scaleA[i] * (SGT_sh + s) / (float)C;
        }
    }
    #pragma unroll
    for (int d = 32; d > 0; d >>= 1) {
        pi += __shfl_down(pi, d);
        vf += __shfl_down(vf, d);
    }
    if (lane == 0) { red2f[wid] = pi; red2i[wid] = vf; }
    __syncthreads();
    if (tid == 0) {
        float s8 = 0.f; int c8 = 0;
        #pragma unroll
        for (int w = 0; w < 8; ++w) { s8 += red2f[w]; c8 += red2i[w]; }
        rank_part[k] = s8;
        npair_part[k] = c8;
    }
}

// K3: combine 512-entry partial arrays in double; write scalar loss.
__global__ __launch_bounds__(512) void final_kernel(
    const float* __restrict__ nll_part, const int* __restrict__ ev_part,
    const float* __restrict__ rank_part, const int* __restrict__ npair_part,
    float* __restrict__ out, int N)
{
    __shared__ double sd1[NBLK];
    __shared__ double sd2[NBLK];
    __shared__ int si1[NBLK];
    __shared__ int si2[NBLK];
    const int t = threadIdx.x;
    sd1[t] = (double)nll_part[t];
    sd2[t] = (double)rank_part[t];
    si1[t] = npair_part[t];
    si2[t] = ev_part[t];
    __syncthreads();
    for (int off = 256; off > 0; off >>= 1) {
        if (t < off) {
            sd1[t] += sd1[t + off];
            sd2[t] += sd2[t + off];
            si1[t] += si1[t + off];
            si2[t] += si2[t + off];
        }
        __syncthreads();
    }
    if (t == 0) {
        double loss = sd1[0] / (double)N;
        if (si2[0] > 1 && si1[0] > 0) loss += 0.5 * sd2[0] / (double)si1[0];
        out[0] = (float)loss;
    }
}

extern "C" void kernel_launch(void* const* d_in, const int* in_sizes, int n_in,
                              void* d_out, int out_size, void* d_ws, size_t ws_size,
                              hipStream_t stream) {
    const float* pmf = (const float*)d_in[0];
    const float* times = (const float*)d_in[1];
    const int* events = (const int*)d_in[2];
    const float* bins = (const float*)d_in[3];
    const int N = in_sizes[1];  // 8192

    char* ws = (char*)d_ws;
    float* SGTp = (float*)(ws + 256);                    // NBLK * TDIM
    float* scaleA = SGTp + (size_t)NBLK * TDIM;          // N
    float* einvA = scaleA + N;                           // N
    float* nll_part = einvA + N;                         // NBLK
    float* rank_part = nll_part + NBLK;                  // TDIM
    int* kidxA = (int*)(rank_part + TDIM);               // N
    int* ev_part = kidxA + N;                            // NBLK
    int* npair_part = ev_part + NBLK;                    // TDIM

    rows_kernel<<<NBLK, 512, 0, stream>>>(
        pmf, times, events, bins, SGTp, scaleA, einvA, kidxA,
        nll_part, ev_part, N);
    bucket_kernel<<<NBLK, 512, 0, stream>>>(
        SGTp, times, events, kidxA, scaleA, einvA,
        rank_part, npair_part, N);
    final_kernel<<<1, 512, 0, stream>>>(
        nll_part, ev_part, rank_part, npair_part, (float*)d_out, N);
}